// Round 15
// baseline (125.762 us; speedup 1.0000x reference)
//
#include <hip/hip_runtime.h>
#include <hip/hip_bf16.h>
#include <math.h>

using bf16 = __hip_bfloat16;
using u16  = unsigned short;

typedef _Float16 f16x8 __attribute__((ext_vector_type(8)));
typedef float    f32x4 __attribute__((ext_vector_type(4)));

#define PIF      3.14159265358979323846f
#define TWO_PIF  6.28318530717958647692f
#define BINW     0.52359877559829887308f   // 2*pi/12
#define HBINW    0.26179938779914943654f   // BINW*0.5

// ---------------------------------------------------------------------------
__global__ void sentinel_kernel(float* out, float val) { out[0] = val; }

// ---------------------------------------------------------------------------
// K0a (big_ws path): pre-split W1 of both heads into f16 hi/lo ([512][512] ea).
// ---------------------------------------------------------------------------
__global__ __launch_bounds__(256) void wsplit_kernel(
    const float* __restrict__ Wb1, const float* __restrict__ Wc1,
    u16* __restrict__ whi, u16* __restrict__ wlo)
{
    const int o = blockIdx.x;
    const float* src = (o < 256) ? (Wb1 + (size_t)o * 512)
                                 : (Wc1 + (size_t)(o - 256) * 512);
    for (int c = threadIdx.x; c < 512; c += 256) {
        const float v = src[c];
        const _Float16 h = (_Float16)v;
        const _Float16 l = (_Float16)(v - (float)h);
        whi[(size_t)o * 512 + c] = *(const u16*)&h;
        wlo[(size_t)o * 512 + c] = *(const u16*)&l;
    }
}

// ---------------------------------------------------------------------------
// K0b (fallback path): transpose W1 into Wt[c][o] f32.
// ---------------------------------------------------------------------------
__global__ __launch_bounds__(256) void wt_kernel(
    const float* __restrict__ Wb1, const float* __restrict__ Wc1,
    float* __restrict__ Wt)               // [512][512]
{
    __shared__ float t[32][33];
    const int tx = threadIdx.x & 31;
    const int ty = threadIdx.x >> 5;
    const int c0 = blockIdx.x * 32;
    const int o0 = blockIdx.y * 32;
#pragma unroll
    for (int r = 0; r < 4; ++r) {
        const int o = o0 + ty + r * 8;
        const float* src = (o < 256) ? (Wb1 + (size_t)o * 512)
                                     : (Wc1 + (size_t)(o - 256) * 512);
        t[ty + r * 8][tx] = src[c0 + tx];
    }
    __syncthreads();
#pragma unroll
    for (int r = 0; r < 4; ++r) {
        const int c = c0 + ty + r * 8;
        Wt[(size_t)c * 512 + o0 + tx] = t[tx][ty + r * 8];
    }
}

// ---------------------------------------------------------------------------
// K1-MFMA (R15): L1 GEMM, f16 split-2 MFMA (x1w1+x1w2+x2w1), f32 accumulate.
// A-fragments from global (L2-resident W); **A loads issued BEFORE the x
// prefetch** so the MFMA's implicit wait is vmcnt(16) (A only), not a full
// drain of the x prefetch (vmcnt in-order — R14's regression mechanism).
// LDS = sX only (20 KB). Tile 128x128, BK=32, 4 waves. Grid (32,4,8).
// ---------------------------------------------------------------------------
__global__ __launch_bounds__(256) void l1_mfma_kernel(
    const float* __restrict__ x,          // [8][512][4096]
    const u16* __restrict__ whi,          // [512][512] f16
    const u16* __restrict__ wlo,          // [512][512] f16
    const float* __restrict__ bb1, const float* __restrict__ sb1,
    const float* __restrict__ tb1,
    const float* __restrict__ bc1, const float* __restrict__ sc1,
    const float* __restrict__ tc1,
    float* __restrict__ hws)              // [8][512][4096] f32
{
    __shared__ _Float16 sX[2][128][40];

    const int tid = threadIdx.x;
    const int n0  = blockIdx.x * 128;
    const int o0  = blockIdx.y * 128;
    const int bz  = blockIdx.z;

    const int wave = tid >> 6;
    const int wr   = wave >> 1;
    const int wc   = wave & 1;
    const int lane = tid & 63;
    const int lr   = lane & 15;
    const int lg   = lane >> 4;

    const float* xb = x + (size_t)bz * 512 * 4096;

    const int srow = tid & 127;
    const int sch  = (tid >> 7) * 16;

    // A-fragment global base: row = o0 + wr*64 + m*16 + lr, col = c0 + lg*8
    const u16* whA = whi + (size_t)(o0 + wr * 64 + lr) * 512 + lg * 8;
    const u16* wlA = wlo + (size_t)(o0 + wr * 64 + lr) * 512 + lg * 8;

    f32x4 acc[4][4];
#pragma unroll
    for (int m = 0; m < 4; ++m)
#pragma unroll
        for (int n = 0; n < 4; ++n) acc[m][n] = (f32x4)(0.0f);

    float px[16];

#pragma unroll
    for (int i = 0; i < 16; ++i)
        px[i] = xb[(size_t)(sch + i) * 4096 + n0 + srow];

    for (int c0 = 0; c0 < 512; c0 += 32) {
        // ---- stage x: split f32 -> f16 hi/lo, write LDS (4 b128 writes)
        {
            f16x8 xa0, xa1, xb0, xb1;
#pragma unroll
            for (int i = 0; i < 8; ++i) {
                float v0 = px[i], v1 = px[i + 8];
                _Float16 h0 = (_Float16)v0;
                _Float16 h1 = (_Float16)v1;
                xa0[i] = h0; xa1[i] = h1;
                xb0[i] = (_Float16)(v0 - (float)h0);
                xb1[i] = (_Float16)(v1 - (float)h1);
            }
            *(f16x8*)&sX[0][srow][sch]     = xa0;
            *(f16x8*)&sX[0][srow][sch + 8] = xa1;
            *(f16x8*)&sX[1][srow][sch]     = xb0;
            *(f16x8*)&sX[1][srow][sch + 8] = xb1;
        }
        __syncthreads();

        // ---- A fragments FIRST (issue order matters: vmcnt is in-order).
        f16x8 A0[4], A1[4], B0[4], B1[4];
#pragma unroll
        for (int m = 0; m < 4; ++m) {
            A0[m] = *(const f16x8*)(whA + (size_t)m * 16 * 512 + c0);
            A1[m] = *(const f16x8*)(wlA + (size_t)m * 16 * 512 + c0);
        }

        // ---- then issue next x chunk prefetch (stays outstanding across MFMA)
        if (c0 + 32 < 512) {
            const int c = c0 + 32;
#pragma unroll
            for (int i = 0; i < 16; ++i)
                px[i] = xb[(size_t)(c + sch + i) * 4096 + n0 + srow];
        }

#pragma unroll
        for (int n = 0; n < 4; ++n) {
            const int row = wc * 64 + n * 16 + lr;
            B0[n] = *(const f16x8*)&sX[0][row][lg * 8];
            B1[n] = *(const f16x8*)&sX[1][row][lg * 8];
        }

#pragma unroll
        for (int m = 0; m < 4; ++m)
#pragma unroll
            for (int n = 0; n < 4; ++n) {
                acc[m][n] = __builtin_amdgcn_mfma_f32_16x16x32_f16(A0[m], B0[n], acc[m][n], 0, 0, 0);
                acc[m][n] = __builtin_amdgcn_mfma_f32_16x16x32_f16(A0[m], B1[n], acc[m][n], 0, 0, 0);
                acc[m][n] = __builtin_amdgcn_mfma_f32_16x16x32_f16(A1[m], B0[n], acc[m][n], 0, 0, 0);
            }
        __syncthreads();
    }

    const float* Ba = (blockIdx.y < 2) ? bb1 : bc1;
    const float* Sa = (blockIdx.y < 2) ? sb1 : sc1;
    const float* Ta = (blockIdx.y < 2) ? tb1 : tc1;
    const int bbase = (blockIdx.y < 2) ? o0 : (o0 - 256);

#pragma unroll
    for (int m = 0; m < 4; ++m) {
#pragma unroll
        for (int r = 0; r < 4; ++r) {
            const int o_l = wr * 64 + m * 16 + lg * 4 + r;
            const float bv = Ba[bbase + o_l];
            const float sv = Sa[bbase + o_l];
            const float tv = Ta[bbase + o_l];
            float* dst = hws + ((size_t)bz * 512 + o0 + o_l) * 4096 + n0;
#pragma unroll
            for (int n = 0; n < 4; ++n) {
                const float v = acc[m][n][r];
                dst[wc * 64 + n * 16 + lr] = fmaxf(fmaf(v + bv, sv, tv), 0.f);
            }
        }
    }
}

// ---------------------------------------------------------------------------
// K2 (R12, verified): L2 + decode. 8 waves, k-sliced, unroll-4, deterministic
// phased reduction. Grid (32, 8), 512 threads. UNCHANGED.
// ---------------------------------------------------------------------------
__global__ __launch_bounds__(512) void l2_decode_kernel(
    const float* __restrict__ hws,        // [8][512][4096] f32
    const float* __restrict__ ctr_preds,  // [8][4096][3]
    const float* __restrict__ mean_size,  // [3][3]
    const float* __restrict__ Wb2, const float* __restrict__ bb2,
    const float* __restrict__ Wc2, const float* __restrict__ bc2,
    float* __restrict__ out_box, float* __restrict__ out_cls,
    float* __restrict__ out_dec)
{
    __shared__ float sw2b[256 * 36];
    __shared__ float sw2c[256 * 4];
    __shared__ float pBox[30 * 128];
    __shared__ float pCls[3 * 128];

    const int tid  = threadIdx.x;
    const int bz   = blockIdx.y;
    const int n0   = blockIdx.x * 128;
    const int wave = tid >> 6;
    const int lane = tid & 63;
    const int nl   = lane * 2;

    {
        const int k = tid & 255;
        if (tid < 256) {
#pragma unroll
            for (int j = 0; j < 15; ++j) sw2b[k * 36 + j] = Wb2[j * 256 + k];
        } else {
#pragma unroll
            for (int j = 15; j < 30; ++j) sw2b[k * 36 + j] = Wb2[j * 256 + k];
            sw2b[k * 36 + 30] = 0.f;
            sw2b[k * 36 + 31] = 0.f;
#pragma unroll
            for (int j = 0; j < 3; ++j) sw2c[k * 4 + j] = Wc2[j * 256 + k];
            sw2c[k * 4 + 3] = 0.f;
        }
    }
    __syncthreads();

    const float* hb = hws + (size_t)bz * 512 * 4096 + n0 + nl;
    const int k0 = wave * 32;

    float accB[32][2];
#pragma unroll
    for (int j = 0; j < 32; ++j) { accB[j][0] = 0.f; accB[j][1] = 0.f; }
    float accC[3][2] = {{0.f,0.f},{0.f,0.f},{0.f,0.f}};

#pragma unroll 4
    for (int kk = 0; kk < 32; ++kk) {
        const int k = k0 + kk;
        const float2 hv = *(const float2*)(hb + (size_t)k * 4096);
#pragma unroll
        for (int j4 = 0; j4 < 8; ++j4) {
            const float4 w = *(const float4*)&sw2b[k * 36 + j4 * 4];
            accB[j4*4+0][0] = fmaf(w.x, hv.x, accB[j4*4+0][0]);
            accB[j4*4+0][1] = fmaf(w.x, hv.y, accB[j4*4+0][1]);
            accB[j4*4+1][0] = fmaf(w.y, hv.x, accB[j4*4+1][0]);
            accB[j4*4+1][1] = fmaf(w.y, hv.y, accB[j4*4+1][1]);
            accB[j4*4+2][0] = fmaf(w.z, hv.x, accB[j4*4+2][0]);
            accB[j4*4+2][1] = fmaf(w.z, hv.y, accB[j4*4+2][1]);
            accB[j4*4+3][0] = fmaf(w.w, hv.x, accB[j4*4+3][0]);
            accB[j4*4+3][1] = fmaf(w.w, hv.y, accB[j4*4+3][1]);
        }
    }
#pragma unroll 4
    for (int kk = 0; kk < 32; ++kk) {
        const int k = k0 + kk;
        const float2 hv = *(const float2*)(hb + (size_t)(256 + k) * 4096);
        const float4 w = *(const float4*)&sw2c[k * 4];
        accC[0][0] = fmaf(w.x, hv.x, accC[0][0]);
        accC[0][1] = fmaf(w.x, hv.y, accC[0][1]);
        accC[1][0] = fmaf(w.y, hv.x, accC[1][0]);
        accC[1][1] = fmaf(w.y, hv.y, accC[1][1]);
        accC[2][0] = fmaf(w.z, hv.x, accC[2][0]);
        accC[2][1] = fmaf(w.z, hv.y, accC[2][1]);
    }
    __syncthreads();

    if (wave == 0) {
#pragma unroll
        for (int j = 0; j < 30; ++j) {
            pBox[j * 128 + nl]     = accB[j][0];
            pBox[j * 128 + nl + 1] = accB[j][1];
        }
#pragma unroll
        for (int j = 0; j < 3; ++j) {
            pCls[j * 128 + nl]     = accC[j][0];
            pCls[j * 128 + nl + 1] = accC[j][1];
        }
    }
    __syncthreads();
#pragma unroll 1
    for (int w = 1; w < 8; ++w) {
        if (wave == w) {
#pragma unroll
            for (int j = 0; j < 30; ++j) {
                pBox[j * 128 + nl]     += accB[j][0];
                pBox[j * 128 + nl + 1] += accB[j][1];
            }
#pragma unroll
            for (int j = 0; j < 3; ++j) {
                pCls[j * 128 + nl]     += accC[j][0];
                pCls[j * 128 + nl + 1] += accC[j][1];
            }
        }
        __syncthreads();
    }

    if (tid < 128) {
        const int nn = tid;
        const size_t gn = (size_t)bz * 4096 + n0 + nn;

        float bp[30];
#pragma unroll
        for (int j = 0; j < 30; ++j) bp[j] = pBox[j * 128 + nn] + bb2[j];
        const float c0v = pCls[0 * 128 + nn] + bc2[0];
        const float c1v = pCls[1 * 128 + nn] + bc2[1];
        const float c2v = pCls[2 * 128 + nn] + bc2[2];

        float* ob = out_box + gn * 30;
#pragma unroll
        for (int j = 0; j < 30; ++j) ob[j] = bp[j];

        out_cls[gn * 3 + 0] = c0v;
        out_cls[gn * 3 + 1] = c1v;
        out_cls[gn * 3 + 2] = c2v;

        int cl = 0; float bv = c0v;
        if (c1v > bv) { bv = c1v; cl = 1; }
        if (c2v > bv) { bv = c2v; cl = 2; }

        const float a0 = mean_size[cl * 3 + 0];
        const float a1 = mean_size[cl * 3 + 1];
        const float a2 = mean_size[cl * 3 + 2];
        const float diag = sqrtf(a0 * a0 + a1 * a1);

        const float px = ctr_preds[gn * 3 + 0];
        const float py = ctr_preds[gn * 3 + 1];
        const float pz = ctr_preds[gn * 3 + 2];

        const float cx = px + bp[0] * diag;
        const float cy = py + bp[1] * diag;
        const float cz = pz + bp[2] * a2;
        const float d0 = expf(bp[3]) * a0;
        const float d1 = expf(bp[4]) * a1;
        const float d2 = expf(bp[5]) * a2;

        int bbin = 0; float lb = bp[6];
#pragma unroll
        for (int k = 1; k < 12; ++k) {
            const float v = bp[6 + k];
            if (v > lb) { lb = v; bbin = k; }
        }
        const float r   = bp[18 + bbin];
        const float ang = ((float)bbin + 0.5f) * BINW + r * HBINW - PIF;

        float* od = out_dec + gn * 7;
        od[0] = cx; od[1] = cy; od[2] = cz;
        od[3] = d0; od[4] = d1; od[5] = d2;
        od[6] = ang;
    }
}

// ---------------------------------------------------------------------------
// Fallback fused head kernel (verified R6), used when ws too small.
// ---------------------------------------------------------------------------
__global__ __launch_bounds__(512) void head_kernel(
    const float* __restrict__ x, const float* __restrict__ Wt,
    const float* __restrict__ bb1, const float* __restrict__ sb1,
    const float* __restrict__ tb1,
    const float* __restrict__ bc1, const float* __restrict__ sc1,
    const float* __restrict__ tc1,
    const float* __restrict__ Wb2, const float* __restrict__ bb2,
    const float* __restrict__ Wc2, const float* __restrict__ bc2,
    const float* __restrict__ ctr_preds, const float* __restrict__ mean_size,
    float* __restrict__ out_box, float* __restrict__ out_cls,
    float* __restrict__ out_dec)
{
    __shared__ float sW[16 * 512];
    __shared__ float sX[16 * 32];
    __shared__ float sH[512 * 33];
    __shared__ float sO[33 * 32];

    const int tid = threadIdx.x;
    const int bz  = blockIdx.y;
    const int n0  = blockIdx.x * 32;
    const int ty = tid >> 2;
    const int tx = tid & 3;
    const float* xb = x + (size_t)bz * 512 * 4096;
    const int xk = tid >> 3;
    const int xn = (tid & 7) * 4;

    float acc[4][8];
#pragma unroll
    for (int i = 0; i < 4; ++i)
#pragma unroll
        for (int j = 0; j < 8; ++j) acc[i][j] = 0.f;

    float4 pw0, pw1, pw2, pw3, pxv;
    {
        const float* wsrc = Wt;
        pw0 = *(const float4*)(wsrc + 4 * tid);
        pw1 = *(const float4*)(wsrc + 4 * tid + 2048);
        pw2 = *(const float4*)(wsrc + 4 * tid + 4096);
        pw3 = *(const float4*)(wsrc + 4 * tid + 6144);
        if (tid < 128)
            pxv = *(const float4*)(xb + (size_t)xk * 4096 + n0 + xn);
    }

    for (int c0 = 0; c0 < 512; c0 += 16) {
        *(float4*)&sW[4 * tid]        = pw0;
        *(float4*)&sW[4 * tid + 2048] = pw1;
        *(float4*)&sW[4 * tid + 4096] = pw2;
        *(float4*)&sW[4 * tid + 6144] = pw3;
        if (tid < 128) *(float4*)&sX[4 * tid] = pxv;
        __syncthreads();

        if (c0 + 16 < 512) {
            const float* wsrc = Wt + (size_t)(c0 + 16) * 512;
            pw0 = *(const float4*)(wsrc + 4 * tid);
            pw1 = *(const float4*)(wsrc + 4 * tid + 2048);
            pw2 = *(const float4*)(wsrc + 4 * tid + 4096);
            pw3 = *(const float4*)(wsrc + 4 * tid + 6144);
            if (tid < 128)
                pxv = *(const float4*)(xb + (size_t)(c0 + 16 + xk) * 4096 + n0 + xn);
        }

#pragma unroll
        for (int k = 0; k < 16; ++k) {
            float a[4], b[8];
            *(float4*)&a[0] = *(const float4*)&sW[k * 512 + ty * 4];
            *(float4*)&b[0] = *(const float4*)&sX[k * 32 + tx * 8];
            *(float4*)&b[4] = *(const float4*)&sX[k * 32 + tx * 8 + 4];
#pragma unroll
            for (int i = 0; i < 4; ++i)
#pragma unroll
                for (int j = 0; j < 8; ++j)
                    acc[i][j] = fmaf(a[i], b[j], acc[i][j]);
        }
        __syncthreads();
    }

#pragma unroll
    for (int i = 0; i < 4; ++i) {
        const int o = ty * 4 + i;
        float bv, sv, tv;
        if (o < 256) { bv = bb1[o];       sv = sb1[o];       tv = tb1[o]; }
        else         { bv = bc1[o - 256]; sv = sc1[o - 256]; tv = tc1[o - 256]; }
        float hv[8];
#pragma unroll
        for (int j = 0; j < 8; ++j)
            hv[j] = fmaxf(fmaf(acc[i][j] + bv, sv, tv), 0.f);
        *(float4*)&sH[o * 33 + tx * 8]     = *(float4*)&hv[0];
        *(float4*)&sH[o * 33 + tx * 8 + 4] = *(float4*)&hv[4];
    }
    __syncthreads();

    for (int p = tid; p < 33 * 32; p += 512) {
        const int ja = p >> 5;
        const int n  = p & 31;
        const float* w2; float bias; int hoff;
        if (ja < 30) { w2 = Wb2 + (size_t)ja * 256;        bias = bb2[ja];      hoff = 0;   }
        else         { w2 = Wc2 + (size_t)(ja - 30) * 256; bias = bc2[ja - 30]; hoff = 256; }
        float a2 = 0.f;
#pragma unroll 8
        for (int o = 0; o < 256; ++o)
            a2 = fmaf(w2[o], sH[(hoff + o) * 33 + n], a2);
        sO[ja * 32 + n] = a2 + bias;
    }
    __syncthreads();

    if (tid < 32) {
        const int nn = tid;
        const size_t gn = (size_t)bz * 4096 + n0 + nn;

        float* ob = out_box + gn * 30;
#pragma unroll
        for (int j = 0; j < 30; ++j) ob[j] = sO[j * 32 + nn];

        const float c0v = sO[30 * 32 + nn];
        const float c1v = sO[31 * 32 + nn];
        const float c2v = sO[32 * 32 + nn];
        out_cls[gn * 3 + 0] = c0v;
        out_cls[gn * 3 + 1] = c1v;
        out_cls[gn * 3 + 2] = c2v;

        int cl = 0; float bv = c0v;
        if (c1v > bv) { bv = c1v; cl = 1; }
        if (c2v > bv) { bv = c2v; cl = 2; }

        const float a0 = mean_size[cl * 3 + 0];
        const float a1 = mean_size[cl * 3 + 1];
        const float a2 = mean_size[cl * 3 + 2];
        const float diag = sqrtf(a0 * a0 + a1 * a1);

        const float px = ctr_preds[gn * 3 + 0];
        const float py = ctr_preds[gn * 3 + 1];
        const float pz = ctr_preds[gn * 3 + 2];

        const float cx = px + sO[0 * 32 + nn] * diag;
        const float cy = py + sO[1 * 32 + nn] * diag;
        const float cz = pz + sO[2 * 32 + nn] * a2;
        const float d0 = expf(sO[3 * 32 + nn]) * a0;
        const float d1 = expf(sO[4 * 32 + nn]) * a1;
        const float d2 = expf(sO[5 * 32 + nn]) * a2;

        int bbin = 0; float lb = sO[6 * 32 + nn];
        for (int k = 1; k < 12; ++k) {
            const float v = sO[(6 + k) * 32 + nn];
            if (v > lb) { lb = v; bbin = k; }
        }
        const float r   = sO[(18 + bbin) * 32 + nn];
        const float ang = ((float)bbin + 0.5f) * BINW + r * HBINW - PIF;

        float* od = out_dec + gn * 7;
        od[0] = cx; od[1] = cy; od[2] = cz;
        od[3] = d0; od[4] = d1; od[5] = d2;
        od[6] = ang;
    }
}

// ---------------------------------------------------------------------------
// K3 (R13, verified): all four assigns in ONE launch. Grid (112, 8).
// ---------------------------------------------------------------------------
__global__ __launch_bounds__(256) void assign_all_kernel(
    const float* __restrict__ ctr_preds, const float* __restrict__ ctr_origins,
    const float* __restrict__ sa_pts0,   const float* __restrict__ sa_pts1,
    const float* __restrict__ gt_boxes,
    const int*   __restrict__ gt_labels,
    const float* __restrict__ mean_size,
    const float* __restrict__ gt_ext, const float* __restrict__ org_ext,
    const float* __restrict__ sa_ext,
    float* __restrict__ a_idx, float* __restrict__ a_cl,
    float* __restrict__ a_fgb, float* __restrict__ a_lab,
    float* __restrict__ b_idx, float* __restrict__ b_cl,
    float* __restrict__ b_fgb, float* __restrict__ b_lab,
    float* __restrict__ c_idx, float* __restrict__ c_cl,
    float* __restrict__ c_fgb,
    float* __restrict__ d_idx, float* __restrict__ d_cl,
    float* __restrict__ d_fgb)
{
    const int bx = blockIdx.x;
    const float* pts; const float* ext;
    int Npts, ignore, retlab, nblk;
    float *out_idx, *out_cls, *out_fgb, *out_lab;

    if (bx < 16) {
        pts = ctr_preds;   ext = gt_ext;  Npts = 4096;  ignore = 1; retlab = 1;
        nblk = bx;
        out_idx = a_idx; out_cls = a_cl; out_fgb = a_fgb; out_lab = a_lab;
    } else if (bx < 32) {
        pts = ctr_origins; ext = org_ext; Npts = 4096;  ignore = 0; retlab = 1;
        nblk = bx - 16;
        out_idx = b_idx; out_cls = b_cl; out_fgb = b_fgb; out_lab = b_lab;
    } else if (bx < 96) {
        pts = sa_pts0;     ext = sa_ext;  Npts = 16384; ignore = 1; retlab = 0;
        nblk = bx - 32;
        out_idx = c_idx; out_cls = c_cl; out_fgb = c_fgb; out_lab = nullptr;
    } else {
        pts = sa_pts1;     ext = sa_ext;  Npts = 4096;  ignore = 0; retlab = 0;
        nblk = bx - 96;
        out_idx = d_idx; out_cls = d_cl; out_fgb = d_fgb; out_lab = nullptr;
    }

    __shared__ float sc[64][4];
    __shared__ float srot[64][2];
    __shared__ float shr[64][4];
    __shared__ float she[64][4];
    __shared__ float sdim[64][4];
    __shared__ float sang[64];
    __shared__ int   slab[64];

    const int tid = threadIdx.x;
    const int b   = blockIdx.y;

    if (tid < 64) {
        const float* bxp = gt_boxes + ((size_t)b * 64 + tid) * 7;
        const float cx = bxp[0], cy = bxp[1], cz = bxp[2];
        const float d0 = bxp[3], d1 = bxp[4], d2 = bxp[5], hd = bxp[6];
        sc[tid][0] = cx; sc[tid][1] = cy; sc[tid][2] = cz;
        srot[tid][0] = cosf(hd); srot[tid][1] = sinf(hd);
        shr[tid][0] = d0 * 0.5f; shr[tid][1] = d1 * 0.5f; shr[tid][2] = d2 * 0.5f;
        she[tid][0] = (d0 + ext[0]) * 0.5f;
        she[tid][1] = (d1 + ext[1]) * 0.5f;
        she[tid][2] = (d2 + ext[2]) * 0.5f;
        sdim[tid][0] = d0; sdim[tid][1] = d1; sdim[tid][2] = d2;
        sang[tid] = hd;
        slab[tid] = gt_labels[b * 64 + tid];
    }
    __syncthreads();

    const int n = nblk * 256 + tid;
    if (n >= Npts) return;
    const size_t gp = (size_t)b * Npts + n;

    const float px = pts[gp * 3 + 0];
    const float py = pts[gp * 3 + 1];
    const float pz = pts[gp * 3 + 2];

    int idxr = -1, idxe = -1;
    for (int j = 0; j < 64; ++j) {
        const float rx = px - sc[j][0];
        const float ry = py - sc[j][1];
        const float rz = pz - sc[j][2];
        const float ct = srot[j][0], st = srot[j][1];
        const float lx = rx * ct + ry * st;
        const float ly = -rx * st + ry * ct;
        const float ax = fabsf(lx), ay = fabsf(ly), az = fabsf(rz);
        const bool inr = (ax <= shr[j][0]) && (ay <= shr[j][1]) && (az <= shr[j][2]);
        const bool ine = (ax <= she[j][0]) && (ay <= she[j][1]) && (az <= she[j][2]);
        if (inr && idxr < 0) idxr = j;
        if (ine && idxe < 0) idxe = j;
    }

    const bool fgr = idxr >= 0;
    const bool fge = idxe >= 0;
    int idx, cls;
    bool fg;
    if (ignore) {
        idx = idxr; fg = fgr;
        cls = (fgr != fge) ? -1 : 0;
    } else {
        idx = fgr ? idxr : idxe; fg = fge;
        cls = 0;
    }
    const int ic  = (idx < 0) ? 0 : idx;
    const int lab = slab[ic];
    if (fg) cls = lab;
    fg = fg && (cls != 0);

    out_idx[gp] = (float)idx;
    out_cls[gp] = (float)cls;

    const float m = fg ? 1.f : 0.f;
    float* fb = out_fgb + gp * 7;
    fb[0] = m * sc[ic][0];
    fb[1] = m * sc[ic][1];
    fb[2] = m * sc[ic][2];
    fb[3] = m * sdim[ic][0];
    fb[4] = m * sdim[ic][1];
    fb[5] = m * sdim[ic][2];
    fb[6] = m * sang[ic];

    if (retlab) {
        int lc = lab; if (lc < 1) lc = 1; if (lc > 3) lc = 3;
        const float a0 = mean_size[(lc - 1) * 3 + 0];
        const float a1 = mean_size[(lc - 1) * 3 + 1];
        const float a2 = mean_size[(lc - 1) * 3 + 2];
        const float diag = sqrtf(a0 * a0 + a1 * a1);

        const float ct0 = (sc[ic][0] - px) / diag;
        const float ct1 = (sc[ic][1] - py) / diag;
        const float ct2 = (sc[ic][2] - pz) / a2;
        const float dt0 = logf(fmaxf(sdim[ic][0], 0.001f) / a0);
        const float dt1 = logf(fmaxf(sdim[ic][1], 0.001f) / a1);
        const float dt2 = logf(fmaxf(sdim[ic][2], 0.001f) / a2);

        float angm = fmodf(sang[ic] + PIF, TWO_PIF);
        if (angm < 0.f) angm += TWO_PIF;
        float bbf = floorf(angm / BINW);
        bbf = fminf(fmaxf(bbf, 0.f), 11.f);
        const float rr = (angm - (bbf + 0.5f) * BINW) / HBINW;

        float* ol = out_lab + gp * 8;
        ol[0] = m * ct0;
        ol[1] = m * ct1;
        ol[2] = m * ct2;
        ol[3] = m * dt0;
        ol[4] = m * dt1;
        ol[5] = m * dt2;
        ol[6] = m * bbf;
        ol[7] = m * rr;
    }
}

// ---------------------------------------------------------------------------
extern "C" void kernel_launch(void* const* d_in, const int* in_sizes, int n_in,
                              void* d_out, int out_size, void* d_ws, size_t ws_size,
                              hipStream_t stream) {
    (void)out_size;

    static const int kExp[23] = {
        16777216, 98304, 98304, 393216, 98304, 3584, 512, 9, 3, 3, 3,
        131072, 256, 256, 256, 7680, 30, 131072, 256, 256, 256, 768, 3
    };
    bool ok = (n_in == 23);
    if (ok) for (int i = 0; i < 23; ++i) if (in_sizes[i] != kExp[i]) ok = false;
    if (!ok) {
        sentinel_kernel<<<1, 1, 0, stream>>>((float*)d_out, 1.0e6f);
        return;
    }
    const size_t wt_bytes = (size_t)512 * 512 * 4;         // 1 MiB
    const size_t h_bytes  = (size_t)8 * 512 * 4096 * 4;    // 64 MiB
    if (ws_size < wt_bytes) {
        sentinel_kernel<<<1, 1, 0, stream>>>((float*)d_out, 2.0e6f);
        return;
    }
    const bool big_ws = (ws_size >= wt_bytes + h_bytes + 4096);

    const float* ctr_feats   = (const float*)d_in[0];
    const float* ctr_preds   = (const float*)d_in[1];
    const float* ctr_origins = (const float*)d_in[2];
    const float* sa_pts0     = (const float*)d_in[3];
    const float* sa_pts1     = (const float*)d_in[4];
    const float* gt_boxes    = (const float*)d_in[5];
    const int*   gt_labels   = (const int*)d_in[6];
    const float* mean_size   = (const float*)d_in[7];
    const float* gt_ext      = (const float*)d_in[8];
    const float* sa_ext      = (const float*)d_in[9];
    const float* org_ext     = (const float*)d_in[10];
    const float* Wb1 = (const float*)d_in[11];
    const float* bb1 = (const float*)d_in[12];
    const float* sb1 = (const float*)d_in[13];
    const float* tb1 = (const float*)d_in[14];
    const float* Wb2 = (const float*)d_in[15];
    const float* bb2 = (const float*)d_in[16];
    const float* Wc1 = (const float*)d_in[17];
    const float* bc1 = (const float*)d_in[18];
    const float* sc1 = (const float*)d_in[19];
    const float* tc1 = (const float*)d_in[20];
    const float* Wc2 = (const float*)d_in[21];
    const float* bc2 = (const float*)d_in[22];

    float* p = (float*)d_out;
    float* o_box  = p; p += (size_t)8 * 4096 * 30;
    float* o_cls  = p; p += (size_t)8 * 4096 * 3;
    float* o_dec  = p; p += (size_t)8 * 4096 * 7;
    float* a_idx  = p; p += (size_t)8 * 4096;
    float* a_cl   = p; p += (size_t)8 * 4096;
    float* a_fgb  = p; p += (size_t)8 * 4096 * 7;
    float* a_lab  = p; p += (size_t)8 * 4096 * 8;
    float* b_idx  = p; p += (size_t)8 * 4096;
    float* b_cl   = p; p += (size_t)8 * 4096;
    float* b_fgb  = p; p += (size_t)8 * 4096 * 7;
    float* b_lab  = p; p += (size_t)8 * 4096 * 8;
    float* c_idx  = p; p += (size_t)8 * 16384;
    float* c_cl   = p; p += (size_t)8 * 16384;
    float* c_fgb  = p; p += (size_t)8 * 16384 * 7;
    float* d_idx  = p; p += (size_t)8 * 4096;
    float* d_cl   = p; p += (size_t)8 * 4096;
    float* d_fgb  = p; p += (size_t)8 * 4096 * 7;

    float* Wt   = (float*)d_ws;
    u16*   whi  = (u16*)d_ws;                               // [512][512] f16
    u16*   wlo  = whi + (size_t)512 * 512;                  // [512][512] f16
    float* hws  = (float*)((char*)d_ws + wt_bytes);

    if (big_ws) {
        wsplit_kernel<<<512, 256, 0, stream>>>(Wb1, Wc1, whi, wlo);

        dim3 g1(32, 4, 8);
        l1_mfma_kernel<<<g1, 256, 0, stream>>>(
            ctr_feats, whi, wlo, bb1, sb1, tb1, bc1, sc1, tc1, hws);

        dim3 g2(32, 8);
        l2_decode_kernel<<<g2, 512, 0, stream>>>(
            hws, ctr_preds, mean_size, Wb2, bb2, Wc2, bc2,
            o_box, o_cls, o_dec);
    } else {
        dim3 gt(16, 16);
        wt_kernel<<<gt, 256, 0, stream>>>(Wb1, Wc1, Wt);
        dim3 gh(128, 8);
        head_kernel<<<gh, 512, 0, stream>>>(
            ctr_feats, Wt, bb1, sb1, tb1, bc1, sc1, tc1,
            Wb2, bb2, Wc2, bc2, ctr_preds, mean_size,
            o_box, o_cls, o_dec);
    }

    dim3 gass(112, 8);
    assign_all_kernel<<<gass, 256, 0, stream>>>(
        ctr_preds, ctr_origins, sa_pts0, sa_pts1,
        gt_boxes, gt_labels, mean_size, gt_ext, org_ext, sa_ext,
        a_idx, a_cl, a_fgb, a_lab,
        b_idx, b_cl, b_fgb, b_lab,
        c_idx, c_cl, c_fgb,
        d_idx, d_cl, d_fgb);
}

// Round 16
// 111.955 us; speedup vs baseline: 1.1233x; 1.1233x over previous
//
#include <hip/hip_runtime.h>
#include <hip/hip_bf16.h>
#include <math.h>

using bf16 = __hip_bfloat16;
using u16  = unsigned short;

typedef _Float16 f16x8 __attribute__((ext_vector_type(8)));
typedef float    f32x4 __attribute__((ext_vector_type(4)));

#define PIF      3.14159265358979323846f
#define TWO_PIF  6.28318530717958647692f
#define BINW     0.52359877559829887308f   // 2*pi/12
#define HBINW    0.26179938779914943654f   // BINW*0.5

// ---------------------------------------------------------------------------
__global__ void sentinel_kernel(float* out, float val) { out[0] = val; }

// ---------------------------------------------------------------------------
// K0a (big_ws path): pre-split W1 of both heads into f16 hi/lo ([512][512] ea).
// ---------------------------------------------------------------------------
__global__ __launch_bounds__(256) void wsplit_kernel(
    const float* __restrict__ Wb1, const float* __restrict__ Wc1,
    u16* __restrict__ whi, u16* __restrict__ wlo)
{
    const int o = blockIdx.x;
    const float* src = (o < 256) ? (Wb1 + (size_t)o * 512)
                                 : (Wc1 + (size_t)(o - 256) * 512);
    for (int c = threadIdx.x; c < 512; c += 256) {
        const float v = src[c];
        const _Float16 h = (_Float16)v;
        const _Float16 l = (_Float16)(v - (float)h);
        whi[(size_t)o * 512 + c] = *(const u16*)&h;
        wlo[(size_t)o * 512 + c] = *(const u16*)&l;
    }
}

// ---------------------------------------------------------------------------
// K0b (fallback path): transpose W1 into Wt[c][o] f32.
// ---------------------------------------------------------------------------
__global__ __launch_bounds__(256) void wt_kernel(
    const float* __restrict__ Wb1, const float* __restrict__ Wc1,
    float* __restrict__ Wt)               // [512][512]
{
    __shared__ float t[32][33];
    const int tx = threadIdx.x & 31;
    const int ty = threadIdx.x >> 5;
    const int c0 = blockIdx.x * 32;
    const int o0 = blockIdx.y * 32;
#pragma unroll
    for (int r = 0; r < 4; ++r) {
        const int o = o0 + ty + r * 8;
        const float* src = (o < 256) ? (Wb1 + (size_t)o * 512)
                                     : (Wc1 + (size_t)(o - 256) * 512);
        t[ty + r * 8][tx] = src[c0 + tx];
    }
    __syncthreads();
#pragma unroll
    for (int r = 0; r < 4; ++r) {
        const int c = c0 + ty + r * 8;
        Wt[(size_t)c * 512 + o0 + tx] = t[tx][ty + r * 8];
    }
}

// ---------------------------------------------------------------------------
// K1-MFMA (R13 exact, verified 77us): L1 GEMM, f16 split-2 MFMA, f32 accum.
// W pre-split staged via LDS (full-chunk prefetch slack); x split in-kernel.
// Tile 128(o) x 128(n), BK=32, 256 threads = 4 waves. Grid (32,4,8).
// ---------------------------------------------------------------------------
__global__ __launch_bounds__(256) void l1_mfma_kernel(
    const float* __restrict__ x,          // [8][512][4096]
    const u16* __restrict__ whi,          // [512][512] f16
    const u16* __restrict__ wlo,          // [512][512] f16
    const float* __restrict__ bb1, const float* __restrict__ sb1,
    const float* __restrict__ tb1,
    const float* __restrict__ bc1, const float* __restrict__ sc1,
    const float* __restrict__ tc1,
    float* __restrict__ hws)              // [8][512][4096] f32
{
    __shared__ _Float16 sW[2][128][40];
    __shared__ _Float16 sX[2][128][40];

    const int tid = threadIdx.x;
    const int n0  = blockIdx.x * 128;
    const int o0  = blockIdx.y * 128;
    const int bz  = blockIdx.z;

    const int wave = tid >> 6;
    const int wr   = wave >> 1;
    const int wc   = wave & 1;
    const int lane = tid & 63;
    const int lr   = lane & 15;
    const int lg   = lane >> 4;

    const float* xb = x + (size_t)bz * 512 * 4096;

    const int srow = tid & 127;
    const int sch  = (tid >> 7) * 16;
    const size_t wrow = (size_t)(o0 + srow) * 512;

    f32x4 acc[4][4];
#pragma unroll
    for (int m = 0; m < 4; ++m)
#pragma unroll
        for (int n = 0; n < 4; ++n) acc[m][n] = (f32x4)(0.0f);

    float px[16];
    uint4 ph0, ph1, pl0, pl1;

#pragma unroll
    for (int i = 0; i < 16; ++i)
        px[i] = xb[(size_t)(sch + i) * 4096 + n0 + srow];
    ph0 = *(const uint4*)(whi + wrow + sch);
    ph1 = *(const uint4*)(whi + wrow + sch + 8);
    pl0 = *(const uint4*)(wlo + wrow + sch);
    pl1 = *(const uint4*)(wlo + wrow + sch + 8);

    for (int c0 = 0; c0 < 512; c0 += 32) {
        // ---- stage: x split f32 -> f16 hi/lo; W already split (pure writes)
        {
            f16x8 xa0, xa1, xb0, xb1;
#pragma unroll
            for (int i = 0; i < 8; ++i) {
                float v0 = px[i], v1 = px[i + 8];
                _Float16 h0 = (_Float16)v0;
                _Float16 h1 = (_Float16)v1;
                xa0[i] = h0; xa1[i] = h1;
                xb0[i] = (_Float16)(v0 - (float)h0);
                xb1[i] = (_Float16)(v1 - (float)h1);
            }
            *(f16x8*)&sX[0][srow][sch]     = xa0;
            *(f16x8*)&sX[0][srow][sch + 8] = xa1;
            *(f16x8*)&sX[1][srow][sch]     = xb0;
            *(f16x8*)&sX[1][srow][sch + 8] = xb1;

            *(uint4*)&sW[0][srow][sch]     = ph0;
            *(uint4*)&sW[0][srow][sch + 8] = ph1;
            *(uint4*)&sW[1][srow][sch]     = pl0;
            *(uint4*)&sW[1][srow][sch + 8] = pl1;
        }
        __syncthreads();

        if (c0 + 32 < 512) {
            const int c = c0 + 32;
#pragma unroll
            for (int i = 0; i < 16; ++i)
                px[i] = xb[(size_t)(c + sch + i) * 4096 + n0 + srow];
            ph0 = *(const uint4*)(whi + wrow + c + sch);
            ph1 = *(const uint4*)(whi + wrow + c + sch + 8);
            pl0 = *(const uint4*)(wlo + wrow + c + sch);
            pl1 = *(const uint4*)(wlo + wrow + c + sch + 8);
        }

        f16x8 A0[4], A1[4], B0[4], B1[4];
#pragma unroll
        for (int m = 0; m < 4; ++m) {
            const int row = wr * 64 + m * 16 + lr;
            A0[m] = *(const f16x8*)&sW[0][row][lg * 8];
            A1[m] = *(const f16x8*)&sW[1][row][lg * 8];
        }
#pragma unroll
        for (int n = 0; n < 4; ++n) {
            const int row = wc * 64 + n * 16 + lr;
            B0[n] = *(const f16x8*)&sX[0][row][lg * 8];
            B1[n] = *(const f16x8*)&sX[1][row][lg * 8];
        }

#pragma unroll
        for (int m = 0; m < 4; ++m)
#pragma unroll
            for (int n = 0; n < 4; ++n) {
                acc[m][n] = __builtin_amdgcn_mfma_f32_16x16x32_f16(A0[m], B0[n], acc[m][n], 0, 0, 0);
                acc[m][n] = __builtin_amdgcn_mfma_f32_16x16x32_f16(A0[m], B1[n], acc[m][n], 0, 0, 0);
                acc[m][n] = __builtin_amdgcn_mfma_f32_16x16x32_f16(A1[m], B0[n], acc[m][n], 0, 0, 0);
            }
        __syncthreads();
    }

    const float* Ba = (blockIdx.y < 2) ? bb1 : bc1;
    const float* Sa = (blockIdx.y < 2) ? sb1 : sc1;
    const float* Ta = (blockIdx.y < 2) ? tb1 : tc1;
    const int bbase = (blockIdx.y < 2) ? o0 : (o0 - 256);

#pragma unroll
    for (int m = 0; m < 4; ++m) {
#pragma unroll
        for (int r = 0; r < 4; ++r) {
            const int o_l = wr * 64 + m * 16 + lg * 4 + r;
            const float bv = Ba[bbase + o_l];
            const float sv = Sa[bbase + o_l];
            const float tv = Ta[bbase + o_l];
            float* dst = hws + ((size_t)bz * 512 + o0 + o_l) * 4096 + n0;
#pragma unroll
            for (int n = 0; n < 4; ++n) {
                const float v = acc[m][n][r];
                dst[wc * 64 + n * 16 + lr] = fmaxf(fmaf(v + bv, sv, tv), 0.f);
            }
        }
    }
}

// ---------------------------------------------------------------------------
// K2 (R16): L2 + decode, 64-point tiles for 3x TLP (24 waves/CU).
// Grid (64, 8), 512 threads = 8 waves; wave w owns k-slice [w*32, w*32+32)
// of both heads; 1 point/lane; deterministic 8-phase reduction.
// LDS: sw2b 36.9K + sw2c 4K + pBox 7.5K + pCls 0.75K = 48.5KB -> 3 blocks/CU.
// ---------------------------------------------------------------------------
__global__ __launch_bounds__(512) void l2_decode_kernel(
    const float* __restrict__ hws,        // [8][512][4096] f32
    const float* __restrict__ ctr_preds,  // [8][4096][3]
    const float* __restrict__ mean_size,  // [3][3]
    const float* __restrict__ Wb2, const float* __restrict__ bb2,
    const float* __restrict__ Wc2, const float* __restrict__ bc2,
    float* __restrict__ out_box, float* __restrict__ out_cls,
    float* __restrict__ out_dec)
{
    __shared__ float sw2b[256 * 36];
    __shared__ float sw2c[256 * 4];
    __shared__ float pBox[30 * 64];
    __shared__ float pCls[3 * 64];

    const int tid  = threadIdx.x;
    const int bz   = blockIdx.y;
    const int n0   = blockIdx.x * 64;
    const int wave = tid >> 6;            // 0..7
    const int lane = tid & 63;

    {
        const int k = tid & 255;
        if (tid < 256) {
#pragma unroll
            for (int j = 0; j < 15; ++j) sw2b[k * 36 + j] = Wb2[j * 256 + k];
        } else {
#pragma unroll
            for (int j = 15; j < 30; ++j) sw2b[k * 36 + j] = Wb2[j * 256 + k];
            sw2b[k * 36 + 30] = 0.f;
            sw2b[k * 36 + 31] = 0.f;
#pragma unroll
            for (int j = 0; j < 3; ++j) sw2c[k * 4 + j] = Wc2[j * 256 + k];
            sw2c[k * 4 + 3] = 0.f;
        }
    }
    __syncthreads();

    const float* hb = hws + (size_t)bz * 512 * 4096 + n0 + lane;
    const int k0 = wave * 32;

    float accB[32];
#pragma unroll
    for (int j = 0; j < 32; ++j) accB[j] = 0.f;
    float accC[3] = {0.f, 0.f, 0.f};

    // box head: h rows k0..k0+31
#pragma unroll 4
    for (int kk = 0; kk < 32; ++kk) {
        const int k = k0 + kk;
        const float hv = hb[(size_t)k * 4096];
#pragma unroll
        for (int j4 = 0; j4 < 8; ++j4) {
            const float4 w = *(const float4*)&sw2b[k * 36 + j4 * 4];
            accB[j4*4+0] = fmaf(w.x, hv, accB[j4*4+0]);
            accB[j4*4+1] = fmaf(w.y, hv, accB[j4*4+1]);
            accB[j4*4+2] = fmaf(w.z, hv, accB[j4*4+2]);
            accB[j4*4+3] = fmaf(w.w, hv, accB[j4*4+3]);
        }
    }
    // cls head: h rows 256+k0 .. 256+k0+31
#pragma unroll 4
    for (int kk = 0; kk < 32; ++kk) {
        const int k = k0 + kk;
        const float hv = hb[(size_t)(256 + k) * 4096];
        const float4 w = *(const float4*)&sw2c[k * 4];
        accC[0] = fmaf(w.x, hv, accC[0]);
        accC[1] = fmaf(w.y, hv, accC[1]);
        accC[2] = fmaf(w.z, hv, accC[2]);
    }
    __syncthreads();

    // ---- deterministic phased reduction (fixed wave order 0..7)
    if (wave == 0) {
#pragma unroll
        for (int j = 0; j < 30; ++j) pBox[j * 64 + lane] = accB[j];
#pragma unroll
        for (int j = 0; j < 3; ++j)  pCls[j * 64 + lane] = accC[j];
    }
    __syncthreads();
#pragma unroll 1
    for (int w = 1; w < 8; ++w) {
        if (wave == w) {
#pragma unroll
            for (int j = 0; j < 30; ++j) pBox[j * 64 + lane] += accB[j];
#pragma unroll
            for (int j = 0; j < 3; ++j)  pCls[j * 64 + lane] += accC[j];
        }
        __syncthreads();
    }

    // ---- decode, 1 thread per point
    if (tid < 64) {
        const int nn = tid;
        const size_t gn = (size_t)bz * 4096 + n0 + nn;

        float bp[30];
#pragma unroll
        for (int j = 0; j < 30; ++j) bp[j] = pBox[j * 64 + nn] + bb2[j];
        const float c0v = pCls[0 * 64 + nn] + bc2[0];
        const float c1v = pCls[1 * 64 + nn] + bc2[1];
        const float c2v = pCls[2 * 64 + nn] + bc2[2];

        float* ob = out_box + gn * 30;
#pragma unroll
        for (int j = 0; j < 30; ++j) ob[j] = bp[j];

        out_cls[gn * 3 + 0] = c0v;
        out_cls[gn * 3 + 1] = c1v;
        out_cls[gn * 3 + 2] = c2v;

        int cl = 0; float bv = c0v;
        if (c1v > bv) { bv = c1v; cl = 1; }
        if (c2v > bv) { bv = c2v; cl = 2; }

        const float a0 = mean_size[cl * 3 + 0];
        const float a1 = mean_size[cl * 3 + 1];
        const float a2 = mean_size[cl * 3 + 2];
        const float diag = sqrtf(a0 * a0 + a1 * a1);

        const float px = ctr_preds[gn * 3 + 0];
        const float py = ctr_preds[gn * 3 + 1];
        const float pz = ctr_preds[gn * 3 + 2];

        const float cx = px + bp[0] * diag;
        const float cy = py + bp[1] * diag;
        const float cz = pz + bp[2] * a2;
        const float d0 = expf(bp[3]) * a0;
        const float d1 = expf(bp[4]) * a1;
        const float d2 = expf(bp[5]) * a2;

        int bbin = 0; float lb = bp[6];
#pragma unroll
        for (int k = 1; k < 12; ++k) {
            const float v = bp[6 + k];
            if (v > lb) { lb = v; bbin = k; }
        }
        const float r   = bp[18 + bbin];
        const float ang = ((float)bbin + 0.5f) * BINW + r * HBINW - PIF;

        float* od = out_dec + gn * 7;
        od[0] = cx; od[1] = cy; od[2] = cz;
        od[3] = d0; od[4] = d1; od[5] = d2;
        od[6] = ang;
    }
}

// ---------------------------------------------------------------------------
// Fallback fused head kernel (verified R6), used when ws too small.
// ---------------------------------------------------------------------------
__global__ __launch_bounds__(512) void head_kernel(
    const float* __restrict__ x, const float* __restrict__ Wt,
    const float* __restrict__ bb1, const float* __restrict__ sb1,
    const float* __restrict__ tb1,
    const float* __restrict__ bc1, const float* __restrict__ sc1,
    const float* __restrict__ tc1,
    const float* __restrict__ Wb2, const float* __restrict__ bb2,
    const float* __restrict__ Wc2, const float* __restrict__ bc2,
    const float* __restrict__ ctr_preds, const float* __restrict__ mean_size,
    float* __restrict__ out_box, float* __restrict__ out_cls,
    float* __restrict__ out_dec)
{
    __shared__ float sW[16 * 512];
    __shared__ float sX[16 * 32];
    __shared__ float sH[512 * 33];
    __shared__ float sO[33 * 32];

    const int tid = threadIdx.x;
    const int bz  = blockIdx.y;
    const int n0  = blockIdx.x * 32;
    const int ty = tid >> 2;
    const int tx = tid & 3;
    const float* xb = x + (size_t)bz * 512 * 4096;
    const int xk = tid >> 3;
    const int xn = (tid & 7) * 4;

    float acc[4][8];
#pragma unroll
    for (int i = 0; i < 4; ++i)
#pragma unroll
        for (int j = 0; j < 8; ++j) acc[i][j] = 0.f;

    float4 pw0, pw1, pw2, pw3, pxv;
    {
        const float* wsrc = Wt;
        pw0 = *(const float4*)(wsrc + 4 * tid);
        pw1 = *(const float4*)(wsrc + 4 * tid + 2048);
        pw2 = *(const float4*)(wsrc + 4 * tid + 4096);
        pw3 = *(const float4*)(wsrc + 4 * tid + 6144);
        if (tid < 128)
            pxv = *(const float4*)(xb + (size_t)xk * 4096 + n0 + xn);
    }

    for (int c0 = 0; c0 < 512; c0 += 16) {
        *(float4*)&sW[4 * tid]        = pw0;
        *(float4*)&sW[4 * tid + 2048] = pw1;
        *(float4*)&sW[4 * tid + 4096] = pw2;
        *(float4*)&sW[4 * tid + 6144] = pw3;
        if (tid < 128) *(float4*)&sX[4 * tid] = pxv;
        __syncthreads();

        if (c0 + 16 < 512) {
            const float* wsrc = Wt + (size_t)(c0 + 16) * 512;
            pw0 = *(const float4*)(wsrc + 4 * tid);
            pw1 = *(const float4*)(wsrc + 4 * tid + 2048);
            pw2 = *(const float4*)(wsrc + 4 * tid + 4096);
            pw3 = *(const float4*)(wsrc + 4 * tid + 6144);
            if (tid < 128)
                pxv = *(const float4*)(xb + (size_t)(c0 + 16 + xk) * 4096 + n0 + xn);
        }

#pragma unroll
        for (int k = 0; k < 16; ++k) {
            float a[4], b[8];
            *(float4*)&a[0] = *(const float4*)&sW[k * 512 + ty * 4];
            *(float4*)&b[0] = *(const float4*)&sX[k * 32 + tx * 8];
            *(float4*)&b[4] = *(const float4*)&sX[k * 32 + tx * 8 + 4];
#pragma unroll
            for (int i = 0; i < 4; ++i)
#pragma unroll
                for (int j = 0; j < 8; ++j)
                    acc[i][j] = fmaf(a[i], b[j], acc[i][j]);
        }
        __syncthreads();
    }

#pragma unroll
    for (int i = 0; i < 4; ++i) {
        const int o = ty * 4 + i;
        float bv, sv, tv;
        if (o < 256) { bv = bb1[o];       sv = sb1[o];       tv = tb1[o]; }
        else         { bv = bc1[o - 256]; sv = sc1[o - 256]; tv = tc1[o - 256]; }
        float hv[8];
#pragma unroll
        for (int j = 0; j < 8; ++j)
            hv[j] = fmaxf(fmaf(acc[i][j] + bv, sv, tv), 0.f);
        *(float4*)&sH[o * 33 + tx * 8]     = *(float4*)&hv[0];
        *(float4*)&sH[o * 33 + tx * 8 + 4] = *(float4*)&hv[4];
    }
    __syncthreads();

    for (int p = tid; p < 33 * 32; p += 512) {
        const int ja = p >> 5;
        const int n  = p & 31;
        const float* w2; float bias; int hoff;
        if (ja < 30) { w2 = Wb2 + (size_t)ja * 256;        bias = bb2[ja];      hoff = 0;   }
        else         { w2 = Wc2 + (size_t)(ja - 30) * 256; bias = bc2[ja - 30]; hoff = 256; }
        float a2 = 0.f;
#pragma unroll 8
        for (int o = 0; o < 256; ++o)
            a2 = fmaf(w2[o], sH[(hoff + o) * 33 + n], a2);
        sO[ja * 32 + n] = a2 + bias;
    }
    __syncthreads();

    if (tid < 32) {
        const int nn = tid;
        const size_t gn = (size_t)bz * 4096 + n0 + nn;

        float* ob = out_box + gn * 30;
#pragma unroll
        for (int j = 0; j < 30; ++j) ob[j] = sO[j * 32 + nn];

        const float c0v = sO[30 * 32 + nn];
        const float c1v = sO[31 * 32 + nn];
        const float c2v = sO[32 * 32 + nn];
        out_cls[gn * 3 + 0] = c0v;
        out_cls[gn * 3 + 1] = c1v;
        out_cls[gn * 3 + 2] = c2v;

        int cl = 0; float bv = c0v;
        if (c1v > bv) { bv = c1v; cl = 1; }
        if (c2v > bv) { bv = c2v; cl = 2; }

        const float a0 = mean_size[cl * 3 + 0];
        const float a1 = mean_size[cl * 3 + 1];
        const float a2 = mean_size[cl * 3 + 2];
        const float diag = sqrtf(a0 * a0 + a1 * a1);

        const float px = ctr_preds[gn * 3 + 0];
        const float py = ctr_preds[gn * 3 + 1];
        const float pz = ctr_preds[gn * 3 + 2];

        const float cx = px + sO[0 * 32 + nn] * diag;
        const float cy = py + sO[1 * 32 + nn] * diag;
        const float cz = pz + sO[2 * 32 + nn] * a2;
        const float d0 = expf(sO[3 * 32 + nn]) * a0;
        const float d1 = expf(sO[4 * 32 + nn]) * a1;
        const float d2 = expf(sO[5 * 32 + nn]) * a2;

        int bbin = 0; float lb = sO[6 * 32 + nn];
        for (int k = 1; k < 12; ++k) {
            const float v = sO[(6 + k) * 32 + nn];
            if (v > lb) { lb = v; bbin = k; }
        }
        const float r   = sO[(18 + bbin) * 32 + nn];
        const float ang = ((float)bbin + 0.5f) * BINW + r * HBINW - PIF;

        float* od = out_dec + gn * 7;
        od[0] = cx; od[1] = cy; od[2] = cz;
        od[3] = d0; od[4] = d1; od[5] = d2;
        od[6] = ang;
    }
}

// ---------------------------------------------------------------------------
// K3 (R13, verified): all four assigns in ONE launch. Grid (112, 8).
// ---------------------------------------------------------------------------
__global__ __launch_bounds__(256) void assign_all_kernel(
    const float* __restrict__ ctr_preds, const float* __restrict__ ctr_origins,
    const float* __restrict__ sa_pts0,   const float* __restrict__ sa_pts1,
    const float* __restrict__ gt_boxes,
    const int*   __restrict__ gt_labels,
    const float* __restrict__ mean_size,
    const float* __restrict__ gt_ext, const float* __restrict__ org_ext,
    const float* __restrict__ sa_ext,
    float* __restrict__ a_idx, float* __restrict__ a_cl,
    float* __restrict__ a_fgb, float* __restrict__ a_lab,
    float* __restrict__ b_idx, float* __restrict__ b_cl,
    float* __restrict__ b_fgb, float* __restrict__ b_lab,
    float* __restrict__ c_idx, float* __restrict__ c_cl,
    float* __restrict__ c_fgb,
    float* __restrict__ d_idx, float* __restrict__ d_cl,
    float* __restrict__ d_fgb)
{
    const int bx = blockIdx.x;
    const float* pts; const float* ext;
    int Npts, ignore, retlab, nblk;
    float *out_idx, *out_cls, *out_fgb, *out_lab;

    if (bx < 16) {
        pts = ctr_preds;   ext = gt_ext;  Npts = 4096;  ignore = 1; retlab = 1;
        nblk = bx;
        out_idx = a_idx; out_cls = a_cl; out_fgb = a_fgb; out_lab = a_lab;
    } else if (bx < 32) {
        pts = ctr_origins; ext = org_ext; Npts = 4096;  ignore = 0; retlab = 1;
        nblk = bx - 16;
        out_idx = b_idx; out_cls = b_cl; out_fgb = b_fgb; out_lab = b_lab;
    } else if (bx < 96) {
        pts = sa_pts0;     ext = sa_ext;  Npts = 16384; ignore = 1; retlab = 0;
        nblk = bx - 32;
        out_idx = c_idx; out_cls = c_cl; out_fgb = c_fgb; out_lab = nullptr;
    } else {
        pts = sa_pts1;     ext = sa_ext;  Npts = 4096;  ignore = 0; retlab = 0;
        nblk = bx - 96;
        out_idx = d_idx; out_cls = d_cl; out_fgb = d_fgb; out_lab = nullptr;
    }

    __shared__ float sc[64][4];
    __shared__ float srot[64][2];
    __shared__ float shr[64][4];
    __shared__ float she[64][4];
    __shared__ float sdim[64][4];
    __shared__ float sang[64];
    __shared__ int   slab[64];

    const int tid = threadIdx.x;
    const int b   = blockIdx.y;

    if (tid < 64) {
        const float* bxp = gt_boxes + ((size_t)b * 64 + tid) * 7;
        const float cx = bxp[0], cy = bxp[1], cz = bxp[2];
        const float d0 = bxp[3], d1 = bxp[4], d2 = bxp[5], hd = bxp[6];
        sc[tid][0] = cx; sc[tid][1] = cy; sc[tid][2] = cz;
        srot[tid][0] = cosf(hd); srot[tid][1] = sinf(hd);
        shr[tid][0] = d0 * 0.5f; shr[tid][1] = d1 * 0.5f; shr[tid][2] = d2 * 0.5f;
        she[tid][0] = (d0 + ext[0]) * 0.5f;
        she[tid][1] = (d1 + ext[1]) * 0.5f;
        she[tid][2] = (d2 + ext[2]) * 0.5f;
        sdim[tid][0] = d0; sdim[tid][1] = d1; sdim[tid][2] = d2;
        sang[tid] = hd;
        slab[tid] = gt_labels[b * 64 + tid];
    }
    __syncthreads();

    const int n = nblk * 256 + tid;
    if (n >= Npts) return;
    const size_t gp = (size_t)b * Npts + n;

    const float px = pts[gp * 3 + 0];
    const float py = pts[gp * 3 + 1];
    const float pz = pts[gp * 3 + 2];

    int idxr = -1, idxe = -1;
    for (int j = 0; j < 64; ++j) {
        const float rx = px - sc[j][0];
        const float ry = py - sc[j][1];
        const float rz = pz - sc[j][2];
        const float ct = srot[j][0], st = srot[j][1];
        const float lx = rx * ct + ry * st;
        const float ly = -rx * st + ry * ct;
        const float ax = fabsf(lx), ay = fabsf(ly), az = fabsf(rz);
        const bool inr = (ax <= shr[j][0]) && (ay <= shr[j][1]) && (az <= shr[j][2]);
        const bool ine = (ax <= she[j][0]) && (ay <= she[j][1]) && (az <= she[j][2]);
        if (inr && idxr < 0) idxr = j;
        if (ine && idxe < 0) idxe = j;
    }

    const bool fgr = idxr >= 0;
    const bool fge = idxe >= 0;
    int idx, cls;
    bool fg;
    if (ignore) {
        idx = idxr; fg = fgr;
        cls = (fgr != fge) ? -1 : 0;
    } else {
        idx = fgr ? idxr : idxe; fg = fge;
        cls = 0;
    }
    const int ic  = (idx < 0) ? 0 : idx;
    const int lab = slab[ic];
    if (fg) cls = lab;
    fg = fg && (cls != 0);

    out_idx[gp] = (float)idx;
    out_cls[gp] = (float)cls;

    const float m = fg ? 1.f : 0.f;
    float* fb = out_fgb + gp * 7;
    fb[0] = m * sc[ic][0];
    fb[1] = m * sc[ic][1];
    fb[2] = m * sc[ic][2];
    fb[3] = m * sdim[ic][0];
    fb[4] = m * sdim[ic][1];
    fb[5] = m * sdim[ic][2];
    fb[6] = m * sang[ic];

    if (retlab) {
        int lc = lab; if (lc < 1) lc = 1; if (lc > 3) lc = 3;
        const float a0 = mean_size[(lc - 1) * 3 + 0];
        const float a1 = mean_size[(lc - 1) * 3 + 1];
        const float a2 = mean_size[(lc - 1) * 3 + 2];
        const float diag = sqrtf(a0 * a0 + a1 * a1);

        const float ct0 = (sc[ic][0] - px) / diag;
        const float ct1 = (sc[ic][1] - py) / diag;
        const float ct2 = (sc[ic][2] - pz) / a2;
        const float dt0 = logf(fmaxf(sdim[ic][0], 0.001f) / a0);
        const float dt1 = logf(fmaxf(sdim[ic][1], 0.001f) / a1);
        const float dt2 = logf(fmaxf(sdim[ic][2], 0.001f) / a2);

        float angm = fmodf(sang[ic] + PIF, TWO_PIF);
        if (angm < 0.f) angm += TWO_PIF;
        float bbf = floorf(angm / BINW);
        bbf = fminf(fmaxf(bbf, 0.f), 11.f);
        const float rr = (angm - (bbf + 0.5f) * BINW) / HBINW;

        float* ol = out_lab + gp * 8;
        ol[0] = m * ct0;
        ol[1] = m * ct1;
        ol[2] = m * ct2;
        ol[3] = m * dt0;
        ol[4] = m * dt1;
        ol[5] = m * dt2;
        ol[6] = m * bbf;
        ol[7] = m * rr;
    }
}

// ---------------------------------------------------------------------------
extern "C" void kernel_launch(void* const* d_in, const int* in_sizes, int n_in,
                              void* d_out, int out_size, void* d_ws, size_t ws_size,
                              hipStream_t stream) {
    (void)out_size;

    static const int kExp[23] = {
        16777216, 98304, 98304, 393216, 98304, 3584, 512, 9, 3, 3, 3,
        131072, 256, 256, 256, 7680, 30, 131072, 256, 256, 256, 768, 3
    };
    bool ok = (n_in == 23);
    if (ok) for (int i = 0; i < 23; ++i) if (in_sizes[i] != kExp[i]) ok = false;
    if (!ok) {
        sentinel_kernel<<<1, 1, 0, stream>>>((float*)d_out, 1.0e6f);
        return;
    }
    const size_t wt_bytes = (size_t)512 * 512 * 4;         // 1 MiB
    const size_t h_bytes  = (size_t)8 * 512 * 4096 * 4;    // 64 MiB
    if (ws_size < wt_bytes) {
        sentinel_kernel<<<1, 1, 0, stream>>>((float*)d_out, 2.0e6f);
        return;
    }
    const bool big_ws = (ws_size >= wt_bytes + h_bytes + 4096);

    const float* ctr_feats   = (const float*)d_in[0];
    const float* ctr_preds   = (const float*)d_in[1];
    const float* ctr_origins = (const float*)d_in[2];
    const float* sa_pts0     = (const float*)d_in[3];
    const float* sa_pts1     = (const float*)d_in[4];
    const float* gt_boxes    = (const float*)d_in[5];
    const int*   gt_labels   = (const int*)d_in[6];
    const float* mean_size   = (const float*)d_in[7];
    const float* gt_ext      = (const float*)d_in[8];
    const float* sa_ext      = (const float*)d_in[9];
    const float* org_ext     = (const float*)d_in[10];
    const float* Wb1 = (const float*)d_in[11];
    const float* bb1 = (const float*)d_in[12];
    const float* sb1 = (const float*)d_in[13];
    const float* tb1 = (const float*)d_in[14];
    const float* Wb2 = (const float*)d_in[15];
    const float* bb2 = (const float*)d_in[16];
    const float* Wc1 = (const float*)d_in[17];
    const float* bc1 = (const float*)d_in[18];
    const float* sc1 = (const float*)d_in[19];
    const float* tc1 = (const float*)d_in[20];
    const float* Wc2 = (const float*)d_in[21];
    const float* bc2 = (const float*)d_in[22];

    float* p = (float*)d_out;
    float* o_box  = p; p += (size_t)8 * 4096 * 30;
    float* o_cls  = p; p += (size_t)8 * 4096 * 3;
    float* o_dec  = p; p += (size_t)8 * 4096 * 7;
    float* a_idx  = p; p += (size_t)8 * 4096;
    float* a_cl   = p; p += (size_t)8 * 4096;
    float* a_fgb  = p; p += (size_t)8 * 4096 * 7;
    float* a_lab  = p; p += (size_t)8 * 4096 * 8;
    float* b_idx  = p; p += (size_t)8 * 4096;
    float* b_cl   = p; p += (size_t)8 * 4096;
    float* b_fgb  = p; p += (size_t)8 * 4096 * 7;
    float* b_lab  = p; p += (size_t)8 * 4096 * 8;
    float* c_idx  = p; p += (size_t)8 * 16384;
    float* c_cl   = p; p += (size_t)8 * 16384;
    float* c_fgb  = p; p += (size_t)8 * 16384 * 7;
    float* d_idx  = p; p += (size_t)8 * 4096;
    float* d_cl   = p; p += (size_t)8 * 4096;
    float* d_fgb  = p; p += (size_t)8 * 4096 * 7;

    float* Wt   = (float*)d_ws;
    u16*   whi  = (u16*)d_ws;                               // [512][512] f16
    u16*   wlo  = whi + (size_t)512 * 512;                  // [512][512] f16
    float* hws  = (float*)((char*)d_ws + wt_bytes);

    if (big_ws) {
        wsplit_kernel<<<512, 256, 0, stream>>>(Wb1, Wc1, whi, wlo);

        dim3 g1(32, 4, 8);
        l1_mfma_kernel<<<g1, 256, 0, stream>>>(
            ctr_feats, whi, wlo, bb1, sb1, tb1, bc1, sc1, tc1, hws);

        dim3 g2(64, 8);
        l2_decode_kernel<<<g2, 512, 0, stream>>>(
            hws, ctr_preds, mean_size, Wb2, bb2, Wc2, bc2,
            o_box, o_cls, o_dec);
    } else {
        dim3 gt(16, 16);
        wt_kernel<<<gt, 256, 0, stream>>>(Wb1, Wc1, Wt);
        dim3 gh(128, 8);
        head_kernel<<<gh, 512, 0, stream>>>(
            ctr_feats, Wt, bb1, sb1, tb1, bc1, sc1, tc1,
            Wb2, bb2, Wc2, bc2, ctr_preds, mean_size,
            o_box, o_cls, o_dec);
    }

    dim3 gass(112, 8);
    assign_all_kernel<<<gass, 256, 0, stream>>>(
        ctr_preds, ctr_origins, sa_pts0, sa_pts1,
        gt_boxes, gt_labels, mean_size, gt_ext, org_ext, sa_ext,
        a_idx, a_cl, a_fgb, a_lab,
        b_idx, b_cl, b_fgb, b_lab,
        c_idx, c_cl, c_fgb,
        d_idx, d_cl, d_fgb);
}